// Round 1
// baseline (476.633 us; speedup 1.0000x reference)
//
#include <hip/hip_runtime.h>
#include <math.h>

// Problem constants (match reference)
#define N_RAYS    131072
#define N_SAMPLES 128
#define BIG_DIST  1e10f
#define EPS       1e-10f

// Output layout (flat concat, all fp32):
//   rgb_map   [R,3]   offset 0
//   disp_map  [R]     offset 393216
//   acc_map   [R]     offset 524288
//   weights   [R,S]   offset 655360
//   depth_map [R]     offset 17432576
#define OFF_RGB    0
#define OFF_DISP   393216
#define OFF_ACC    524288
#define OFF_W      655360
#define OFF_DEPTH  17432576

__global__ __launch_bounds__(256) void nerf_render_kernel(
    const float4* __restrict__ raw,     // [R, S] as float4 (rgb+sigma)
    const float*  __restrict__ z_vals,  // [R, S]
    const float*  __restrict__ rays_d,  // [R, 3]
    float* __restrict__ out)
{
    const int r = blockIdx.x * blockDim.x + threadIdx.x;
    if (r >= N_RAYS) return;

    const float4* rawr = raw + (size_t)r * N_SAMPLES;
    const float4* zr4  = (const float4*)(z_vals + (size_t)r * N_SAMPLES);

    // |rays_d|
    const float dx = rays_d[3 * r + 0];
    const float dy = rays_d[3 * r + 1];
    const float dz = rays_d[3 * r + 2];
    const float nrm = sqrtf(dx * dx + dy * dy + dz * dz);

    float T = 1.0f;            // exclusive transmittance cumprod
    float cr = 0.f, cg = 0.f, cb = 0.f;
    float depth = 0.f, acc = 0.f;

    float* wout = out + OFF_W + (size_t)r * N_SAMPLES;

    // z prefetch: keep current 8 z values + first of next chunk
    float4 z0 = zr4[0];
    float4 z1 = zr4[1];

    for (int c = 0; c < N_SAMPLES / 8; ++c) {
        const int s0 = c * 8;

        // 8 x float4 = one full 128B line of raw per lane per outer iter
        float4 rv[8];
#pragma unroll
        for (int j = 0; j < 8; ++j) rv[j] = rawr[s0 + j];

        float zarr[9];
        zarr[0] = z0.x; zarr[1] = z0.y; zarr[2] = z0.z; zarr[3] = z0.w;
        zarr[4] = z1.x; zarr[5] = z1.y; zarr[6] = z1.z; zarr[7] = z1.w;

        float4 nz0, nz1;
        if (c < N_SAMPLES / 8 - 1) {
            nz0 = zr4[2 * c + 2];
            nz1 = zr4[2 * c + 3];
            zarr[8] = nz0.x;
        } else {
            nz0 = z0; nz1 = z1;      // unused, keep defined
            zarr[8] = 0.0f;          // unused: dist for s=127 is BIG_DIST
        }

        float w8[8];
#pragma unroll
        for (int j = 0; j < 8; ++j) {
            const int s = s0 + j;
            float dist = (s == N_SAMPLES - 1) ? BIG_DIST : (zarr[j + 1] - zarr[j]);
            dist *= nrm;

            const float sigma = fmaxf(rv[j].w, 0.0f);          // relu
            const float alpha = 1.0f - __expf(-sigma * dist);
            const float w = alpha * T;
            T = T * (1.0f - alpha + EPS);

            // sigmoid(rgb)
            const float sr = __builtin_amdgcn_rcpf(1.0f + __expf(-rv[j].x));
            const float sg = __builtin_amdgcn_rcpf(1.0f + __expf(-rv[j].y));
            const float sb = __builtin_amdgcn_rcpf(1.0f + __expf(-rv[j].z));

            cr += w * sr;
            cg += w * sg;
            cb += w * sb;
            depth += w * zarr[j];
            acc += w;
            w8[j] = w;
        }

        // two float4 stores per chunk
        float4* w4 = (float4*)(wout + s0);
        w4[0] = make_float4(w8[0], w8[1], w8[2], w8[3]);
        w4[1] = make_float4(w8[4], w8[5], w8[6], w8[7]);

        z0 = nz0;
        z1 = nz1;
    }

    out[OFF_RGB + 3 * r + 0] = cr;
    out[OFF_RGB + 3 * r + 1] = cg;
    out[OFF_RGB + 3 * r + 2] = cb;
    out[OFF_ACC + r] = acc;
    out[OFF_DEPTH + r] = depth;
    out[OFF_DISP + r] = 1.0f / fmaxf(EPS, depth / acc);
}

extern "C" void kernel_launch(void* const* d_in, const int* in_sizes, int n_in,
                              void* d_out, int out_size, void* d_ws, size_t ws_size,
                              hipStream_t stream) {
    const float4* raw    = (const float4*)d_in[0];
    const float*  z_vals = (const float*)d_in[1];
    const float*  rays_d = (const float*)d_in[2];
    float* out = (float*)d_out;

    const int block = 256;
    const int grid  = (N_RAYS + block - 1) / block;   // 512 blocks
    nerf_render_kernel<<<grid, block, 0, stream>>>(raw, z_vals, rays_d, out);
}

// Round 2
// 410.092 us; speedup vs baseline: 1.1623x; 1.1623x over previous
//
#include <hip/hip_runtime.h>
#include <math.h>

// Problem constants (match reference)
#define N_RAYS    131072
#define N_SAMPLES 128
#define BIG_DIST  1e10f
#define EPS       1e-10f

// Output layout (flat concat, all fp32):
//   rgb_map   [R,3]   offset 0
//   disp_map  [R]     offset 393216
//   acc_map   [R]     offset 524288
//   weights   [R,S]   offset 655360
//   depth_map [R]     offset 17432576
#define OFF_RGB    0
#define OFF_DISP   393216
#define OFF_ACC    524288
#define OFF_W      655360
#define OFF_DEPTH  17432576

// One wave (64 lanes) per ray; lane L owns samples s0=2L, s1=2L+1.
// Exclusive transmittance cumprod via wave-parallel prefix-product scan.
__global__ __launch_bounds__(256) void nerf_render_scan_kernel(
    const float4* __restrict__ raw,     // [R, S] rgb+sigma
    const float*  __restrict__ z_vals,  // [R, S]
    const float*  __restrict__ rays_d,  // [R, 3]
    float* __restrict__ out)
{
    const int tid  = blockIdx.x * blockDim.x + threadIdx.x;
    const int r    = tid >> 6;           // one wave per ray
    const int lane = threadIdx.x & 63;
    if (r >= N_RAYS) return;

    // ---- loads (all coalesced within the wave) ----
    const float4* rawr = raw + (size_t)r * N_SAMPLES;
    const float4  rv0 = rawr[2 * lane];
    const float4  rv1 = rawr[2 * lane + 1];

    const float2* zr2 = (const float2*)(z_vals + (size_t)r * N_SAMPLES);
    const float2  z   = zr2[lane];       // z.x = z[2L], z.y = z[2L+1]

    // z[2L+2] lives in the next lane's z.x (lane 63 unused -> BIG_DIST)
    const float znext = __shfl_down(z.x, 1);

    const float dxx = rays_d[3 * r + 0];
    const float dyy = rays_d[3 * r + 1];
    const float dzz = rays_d[3 * r + 2];
    const float nrm = sqrtf(dxx * dxx + dyy * dyy + dzz * dzz);

    // ---- per-sample alpha ----
    const float dist0 = (z.y - z.x) * nrm;
    const float dist1 = (lane == 63) ? (BIG_DIST * nrm) : ((znext - z.y) * nrm);

    const float sig0 = fmaxf(rv0.w, 0.0f);
    const float sig1 = fmaxf(rv1.w, 0.0f);
    const float a0 = 1.0f - __expf(-sig0 * dist0);
    const float a1 = 1.0f - __expf(-sig1 * dist1);

    const float f0 = 1.0f - a0 + EPS;    // per-sample transmittance factors
    const float f1 = 1.0f - a1 + EPS;
    const float p  = f0 * f1;            // per-lane product

    // ---- inclusive prefix product of p across the wave (6 shfl_up steps) ----
    float sp = p;
#pragma unroll
    for (int off = 1; off < 64; off <<= 1) {
        const float t = __shfl_up(sp, off);
        sp *= (lane >= off) ? t : 1.0f;
    }
    // exclusive prefix: shift by one lane
    float Texc = __shfl_up(sp, 1);
    if (lane == 0) Texc = 1.0f;

    const float T0 = Texc;               // T at sample 2L
    const float T1 = Texc * f0;          // T at sample 2L+1
    const float w0 = a0 * T0;
    const float w1 = a1 * T1;

    // ---- weights store (coalesced float2) ----
    ((float2*)(out + OFF_W + (size_t)r * N_SAMPLES))[lane] = make_float2(w0, w1);

    // ---- per-lane partials for the 5 reductions ----
    const float sr0 = __builtin_amdgcn_rcpf(1.0f + __expf(-rv0.x));
    const float sg0 = __builtin_amdgcn_rcpf(1.0f + __expf(-rv0.y));
    const float sb0 = __builtin_amdgcn_rcpf(1.0f + __expf(-rv0.z));
    const float sr1 = __builtin_amdgcn_rcpf(1.0f + __expf(-rv1.x));
    const float sg1 = __builtin_amdgcn_rcpf(1.0f + __expf(-rv1.y));
    const float sb1 = __builtin_amdgcn_rcpf(1.0f + __expf(-rv1.z));

    float cr    = w0 * sr0 + w1 * sr1;
    float cg    = w0 * sg0 + w1 * sg1;
    float cb    = w0 * sb0 + w1 * sb1;
    float depth = w0 * z.x + w1 * z.y;
    float acc   = w0 + w1;

    // ---- wave butterfly reduction (5 independent chains, good ILP) ----
#pragma unroll
    for (int m = 32; m > 0; m >>= 1) {
        cr    += __shfl_xor(cr, m);
        cg    += __shfl_xor(cg, m);
        cb    += __shfl_xor(cb, m);
        depth += __shfl_xor(depth, m);
        acc   += __shfl_xor(acc, m);
    }

    if (lane == 0) {
        out[OFF_RGB + 3 * r + 0] = cr;
        out[OFF_RGB + 3 * r + 1] = cg;
        out[OFF_RGB + 3 * r + 2] = cb;
        out[OFF_ACC + r]   = acc;
        out[OFF_DEPTH + r] = depth;
        out[OFF_DISP + r]  = 1.0f / fmaxf(EPS, depth / acc);
    }
}

extern "C" void kernel_launch(void* const* d_in, const int* in_sizes, int n_in,
                              void* d_out, int out_size, void* d_ws, size_t ws_size,
                              hipStream_t stream) {
    const float4* raw    = (const float4*)d_in[0];
    const float*  z_vals = (const float*)d_in[1];
    const float*  rays_d = (const float*)d_in[2];
    float* out = (float*)d_out;

    const int block = 256;                       // 4 waves = 4 rays per block
    const int rays_per_block = block / 64;
    const int grid = N_RAYS / rays_per_block;    // 32768 blocks
    nerf_render_scan_kernel<<<grid, block, 0, stream>>>(raw, z_vals, rays_d, out);
}